// Round 6
// baseline (270.676 us; speedup 1.0000x reference)
//
#include <hip/hip_runtime.h>

// Problem constants
constexpr int Bb = 16;      // batch
constexpr int Nn = 256;     // regions
constexpr int Hh = 768;     // hidden
constexpr int Pp = 2048;    // proj dim
constexpr int Rr = 3;       // relation types
constexpr int Mm = Bb * Nn; // 4096 flattened rows
constexpr int HA = 896;     // augmented hidden (768 + 1 bias row + pad)
constexpr int KA = 2080;    // augmented K for Bop GEMM (2048 + 32)
constexpr int JA = Rr * HA; // 2688

typedef __bf16 bf16_t;
typedef __bf16 bf16x8 __attribute__((ext_vector_type(8)));
typedef __bf16 bf16x4 __attribute__((ext_vector_type(4)));
typedef float  floatx4 __attribute__((ext_vector_type(4)));

// async global->LDS, 16B per lane; LDS dest = wave-uniform base + lane*16
__device__ __forceinline__ void gld_lds16(const void* g, void* l) {
    __builtin_amdgcn_global_load_lds(
        (__attribute__((address_space(1))) void*)g,
        (__attribute__((address_space(3))) void*)l,
        16, 0, 0);
}

// ---------------------------------------------------------------------------
// F_aug [4096, 896] bf16: cols 0..767 = F, col 768 = 1, cols 769..895 = 0
// ---------------------------------------------------------------------------
__global__ __launch_bounds__(256) void build_Faug(
    const float* __restrict__ F, bf16_t* __restrict__ out)
{
    const int idx = blockIdx.x * 256 + threadIdx.x;   // over 4096 * (896/4)
    const int n = idx / (HA / 4), c4 = idx % (HA / 4);
    const int h = c4 * 4;
    bf16x4 o;
    if (h < Hh) {
        float4 v = *(const float4*)(F + (size_t)n * Hh + h);
        o = { (bf16_t)v.x, (bf16_t)v.y, (bf16_t)v.z, (bf16_t)v.w };
    } else {
        #pragma unroll
        for (int e = 0; e < 4; ++e) o[e] = (bf16_t)((h + e == Hh) ? 1.0f : 0.0f);
    }
    *(bf16x4*)(out + (size_t)n * HA + h) = o;
}

// ---------------------------------------------------------------------------
// tWaug [896, 2048]: rows j<768 = tW^T (tW[q,j]), row 768 = bt[q], rows>768 = 0
// grid (2048/32, 896/32), block (32,8)
// ---------------------------------------------------------------------------
__global__ __launch_bounds__(256) void build_tWaug(
    const float* __restrict__ tW, const float* __restrict__ bt,
    bf16_t* __restrict__ out)
{
    __shared__ float t[32][33];
    const int j0 = blockIdx.y * 32, q0 = blockIdx.x * 32;
    const int tx = threadIdx.x, ty = threadIdx.y;
    #pragma unroll
    for (int s = 0; s < 4; ++s) {
        const int q = q0 + ty + s * 8, j = j0 + tx;
        t[ty + s * 8][tx] = (j < Hh) ? tW[(size_t)q * Hh + j] : 0.0f;
    }
    __syncthreads();
    #pragma unroll
    for (int s = 0; s < 4; ++s) {
        const int j = j0 + ty + s * 8, q = q0 + tx;
        float v = t[tx][ty + s * 8];
        if (j == Hh) v = bt[q];
        else if (j > Hh) v = 0.0f;
        out[(size_t)j * Pp + q] = (bf16_t)v;
    }
}

// ---------------------------------------------------------------------------
// hWaug [896, 2080]: rows h<768 = hW^T, row 768 = [bh | 1 @ p=2048], rows>768=0
// grid (2080/32, 896/32), block (32,8)
// ---------------------------------------------------------------------------
__global__ __launch_bounds__(256) void build_hWaug(
    const float* __restrict__ hW, const float* __restrict__ bh,
    bf16_t* __restrict__ out)
{
    __shared__ float t[32][33];
    const int h0 = blockIdx.y * 32, p0 = blockIdx.x * 32;
    const int tx = threadIdx.x, ty = threadIdx.y;
    #pragma unroll
    for (int s = 0; s < 4; ++s) {
        const int p = p0 + ty + s * 8, h = h0 + tx;
        t[ty + s * 8][tx] = (p < Pp && h < Hh) ? hW[(size_t)p * Hh + h] : 0.0f;
    }
    __syncthreads();
    #pragma unroll
    for (int s = 0; s < 4; ++s) {
        const int h = h0 + ty + s * 8, p = p0 + tx;
        float v = t[tx][ty + s * 8];
        if (h == Hh) v = (p < Pp) ? bh[p] : (p == Pp ? 1.0f : 0.0f);
        else if (h > Hh) v = 0.0f;
        out[(size_t)h * KA + p] = (bf16_t)v;
    }
}

// ---------------------------------------------------------------------------
// fill T1taug col stripe [j][2048..2079]: col 2048 = (j==768 ? bil_b[r] : 0)
// ---------------------------------------------------------------------------
__global__ __launch_bounds__(256) void fill_T1cols(
    const float* __restrict__ bil_b, bf16_t* __restrict__ T1)
{
    const int idx = blockIdx.x * 256 + threadIdx.x;
    if (idx >= Rr * HA) return;
    const int r = idx / HA, j = idx % HA;
    bf16_t* p = T1 + (size_t)r * HA * KA + (size_t)j * KA + Pp;
    p[0] = (bf16_t)(j == Hh ? bil_b[r] : 0.0f);
    #pragma unroll
    for (int e = 1; e < 32; ++e) p[e] = (bf16_t)0.0f;
}

// ---------------------------------------------------------------------------
// 64x64-tile NT GEMM, A bf16 / B fp32 (in-kernel cvt), double-buffered LDS,
// XOR-swizzled fp32 B staging to kill LDS bank conflicts:
//   LDS[row][g] holds global[row][g ^ (row&7)] (col-groups of 4 floats).
//   Fragment reads XOR the same term back (row&7 == fr&7 since tile offsets
//   are multiples of 8) -> quad-group lanes spread over all 32 banks.
//   C[m,n] = sum_k A[m,k] * B[n,k];  used for T1 = tWaug @ bil_W[r]^T
// 4 waves (2x2), wave = 32x32. grid (N/64, M/64, R)
// ---------------------------------------------------------------------------
__global__ __launch_bounds__(256) void gemm_nt_64_bf32(
    const bf16_t* __restrict__ A, int lda,
    const float*  __restrict__ B, int ldb, size_t sB,
    bf16_t* __restrict__ C, int ldc, size_t sC, int K)
{
    B += (size_t)blockIdx.z * sB;
    C += (size_t)blockIdx.z * sC;

    __shared__ bf16_t As[2][64 * 32];
    __shared__ float  Bs[2][64 * 32];

    const int tid = threadIdx.x;
    const int w = tid >> 6;
    const int l = tid & 63;
    const int m0 = blockIdx.y * 64;
    const int n0 = blockIdx.x * 64;

    // A staging (bf16): row = tid/4, col8 = (tid&3)*8 ; 1 issue (4KB)
    const bf16_t* ga = A + (size_t)(m0 + (tid >> 2)) * lda + ((tid & 3) << 3);
    // B staging (fp32), swizzled source: lane's physical LDS col-group is
    // (tid&7); it must hold global col-group (tid&7)^(row&7).
    const int brow = tid >> 3;                 // 0..31 (+32 for gb1; 32%8==0)
    const int bgrp = (tid & 7) ^ (brow & 7);
    const float* gb0 = B + (size_t)(n0 + brow) * ldb + (bgrp << 2);
    const float* gb1 = gb0 + (size_t)32 * ldb;

    const int wm = (w >> 1) << 5;
    const int wn = (w & 1) << 5;
    const int fr = l & 15;
    const int fq = (l >> 4) << 3;

    // swizzled fragment-read col offsets (in floats), lane constants
    const int swz = fr & 7;
    const int cg0 = (l >> 4) << 1;             // global col-group of fq
    const int off0 = ((cg0 ^ swz) << 2);       // physical offset of fq..fq+3
    const int off1 = (((cg0 + 1) ^ swz) << 2); // physical offset of fq+4..fq+7

    floatx4 acc[2][2] = {};

    // prefetch step 0
    {
        gld_lds16(ga, (char*)As[0] + (w << 10));
        gld_lds16(gb0, (char*)Bs[0] + (w << 10));
        gld_lds16(gb1, (char*)Bs[0] + 4096 + (w << 10));
        ga += 32; gb0 += 32; gb1 += 32;
    }

    const int steps = K >> 5;
    for (int k = 0; k < steps; ++k) {
        __syncthreads();   // drains vmcnt(0): buf[cur] ready; reads of buf[cur^1] done
        const int cur = k & 1;
        if (k + 1 < steps) {
            gld_lds16(ga, (char*)As[cur ^ 1] + (w << 10));
            gld_lds16(gb0, (char*)Bs[cur ^ 1] + (w << 10));
            gld_lds16(gb1, (char*)Bs[cur ^ 1] + 4096 + (w << 10));
            ga += 32; gb0 += 32; gb1 += 32;
        }

        bf16x8 a[2], b[2];
        #pragma unroll
        for (int i = 0; i < 2; ++i)
            a[i] = *(const bf16x8*)&As[cur][(wm + i * 16 + fr) * 32 + fq];
        #pragma unroll
        for (int j = 0; j < 2; ++j) {
            const float* bp = &Bs[cur][(wn + j * 16 + fr) * 32];
            floatx4 x0 = *(const floatx4*)(bp + off0);
            floatx4 x1 = *(const floatx4*)(bp + off1);
            #pragma unroll
            for (int e = 0; e < 4; ++e) { b[j][e] = (bf16_t)x0[e]; b[j][e + 4] = (bf16_t)x1[e]; }
        }
        #pragma unroll
        for (int i = 0; i < 2; ++i)
            #pragma unroll
            for (int j = 0; j < 2; ++j)
                acc[i][j] = __builtin_amdgcn_mfma_f32_16x16x32_bf16(a[i], b[j], acc[i][j], 0, 0, 0);
    }

    const int em = m0 + wm + ((l >> 4) << 2);
    const int en = n0 + wn + (l & 15);
    #pragma unroll
    for (int i = 0; i < 2; ++i)
        #pragma unroll
        for (int j = 0; j < 2; ++j)
            #pragma unroll
            for (int rg = 0; rg < 4; ++rg)
                C[(size_t)(em + i * 16 + rg) * ldc + en + j * 16] = (bf16_t)acc[i][j][rg];
}

// ---------------------------------------------------------------------------
// 64x64-tile bf16 NT GEMM, double-buffered LDS (for Bop)
// ---------------------------------------------------------------------------
__global__ __launch_bounds__(256) void gemm_nt_64(
    const bf16_t* __restrict__ A, int lda, size_t sA,
    const bf16_t* __restrict__ B, int ldb, size_t sB,
    bf16_t* __restrict__ C, int ldc, size_t sC, int K)
{
    A += (size_t)blockIdx.z * sA;
    B += (size_t)blockIdx.z * sB;
    C += (size_t)blockIdx.z * sC;

    __shared__ bf16_t As[2][64 * 32];
    __shared__ bf16_t Bs[2][64 * 32];

    const int tid = threadIdx.x;
    const int w = tid >> 6;
    const int l = tid & 63;
    const int m0 = blockIdx.y * 64;
    const int n0 = blockIdx.x * 64;

    const bf16_t* ga = A + (size_t)(m0 + (tid >> 2)) * lda + ((tid & 3) << 3);
    const bf16_t* gb = B + (size_t)(n0 + (tid >> 2)) * ldb + ((tid & 3) << 3);

    const int wm = (w >> 1) << 5;
    const int wn = (w & 1) << 5;
    const int fr = l & 15;
    const int fq = (l >> 4) << 3;

    floatx4 acc[2][2] = {};

    {
        gld_lds16(ga, (char*)As[0] + (w << 10));
        gld_lds16(gb, (char*)Bs[0] + (w << 10));
        ga += 32; gb += 32;
    }

    const int steps = K >> 5;
    for (int k = 0; k < steps; ++k) {
        __syncthreads();
        const int cur = k & 1;
        if (k + 1 < steps) {
            gld_lds16(ga, (char*)As[cur ^ 1] + (w << 10));
            gld_lds16(gb, (char*)Bs[cur ^ 1] + (w << 10));
            ga += 32; gb += 32;
        }

        bf16x8 a[2], b[2];
        #pragma unroll
        for (int i = 0; i < 2; ++i) {
            a[i] = *(const bf16x8*)&As[cur][(wm + i * 16 + fr) * 32 + fq];
            b[i] = *(const bf16x8*)&Bs[cur][(wn + i * 16 + fr) * 32 + fq];
        }
        #pragma unroll
        for (int i = 0; i < 2; ++i)
            #pragma unroll
            for (int j = 0; j < 2; ++j)
                acc[i][j] = __builtin_amdgcn_mfma_f32_16x16x32_bf16(a[i], b[j], acc[i][j], 0, 0, 0);
    }

    const int em = m0 + wm + ((l >> 4) << 2);
    const int en = n0 + wn + (l & 15);
    #pragma unroll
    for (int i = 0; i < 2; ++i)
        #pragma unroll
        for (int j = 0; j < 2; ++j)
            #pragma unroll
            for (int rg = 0; rg < 4; ++rg)
                C[(size_t)(em + i * 16 + rg) * ldc + en + j * 16] = (bf16_t)acc[i][j][rg];
}

// ---------------------------------------------------------------------------
// 128x128-tile bf16 NT GEMM, double-buffered LDS (for FG)
// 4 waves (2x2), each wave 64x64 = 4x4 MFMA tiles.
// ---------------------------------------------------------------------------
__global__ __launch_bounds__(256) void gemm_nt_128(
    const bf16_t* __restrict__ A, int lda,
    const bf16_t* __restrict__ B, int ldb,
    bf16_t* __restrict__ C, int ldc, int K)
{
    __shared__ bf16_t As[2][128 * 32];
    __shared__ bf16_t Bs[2][128 * 32];

    const int tid = threadIdx.x;
    const int w = tid >> 6;
    const int l = tid & 63;
    const int m0 = blockIdx.y * 128;
    const int n0 = blockIdx.x * 128;

    const int srow = (w << 4) + (l >> 2);
    const int scol = (l & 3) << 3;
    const bf16_t* ga0 = A + (size_t)(m0 + srow) * lda + scol;
    const bf16_t* ga1 = ga0 + (size_t)64 * lda;
    const bf16_t* gb0 = B + (size_t)(n0 + srow) * ldb + scol;
    const bf16_t* gb1 = gb0 + (size_t)64 * ldb;

    const int wm = (w >> 1) << 6;
    const int wn = (w & 1) << 6;
    const int fr = l & 15;
    const int fq = (l >> 4) << 3;

    floatx4 acc[4][4] = {};

    {
        char* a = (char*)As[0] + (w << 10);
        char* b = (char*)Bs[0] + (w << 10);
        gld_lds16(ga0, a); gld_lds16(ga1, a + 4096);
        gld_lds16(gb0, b); gld_lds16(gb1, b + 4096);
        ga0 += 32; ga1 += 32; gb0 += 32; gb1 += 32;
    }

    const int steps = K >> 5;
    for (int k = 0; k < steps; ++k) {
        __syncthreads();
        const int cur = k & 1;
        if (k + 1 < steps) {
            char* a = (char*)As[cur ^ 1] + (w << 10);
            char* b = (char*)Bs[cur ^ 1] + (w << 10);
            gld_lds16(ga0, a); gld_lds16(ga1, a + 4096);
            gld_lds16(gb0, b); gld_lds16(gb1, b + 4096);
            ga0 += 32; ga1 += 32; gb0 += 32; gb1 += 32;
        }

        bf16x8 a[4], b[4];
        #pragma unroll
        for (int i = 0; i < 4; ++i) {
            a[i] = *(const bf16x8*)&As[cur][(wm + i * 16 + fr) * 32 + fq];
            b[i] = *(const bf16x8*)&Bs[cur][(wn + i * 16 + fr) * 32 + fq];
        }
        #pragma unroll
        for (int i = 0; i < 4; ++i)
            #pragma unroll
            for (int j = 0; j < 4; ++j)
                acc[i][j] = __builtin_amdgcn_mfma_f32_16x16x32_bf16(a[i], b[j], acc[i][j], 0, 0, 0);
    }

    const int em = m0 + wm + ((l >> 4) << 2);
    const int en = n0 + wn + (l & 15);
    #pragma unroll
    for (int j = 0; j < 4; ++j) {
        const int n = en + j * 16;
        #pragma unroll
        for (int i = 0; i < 4; ++i) {
            #pragma unroll
            for (int rg = 0; rg < 4; ++rg)
                C[(size_t)(em + i * 16 + rg) * ldc + n] = (bf16_t)(acc[i][j][rg]);
        }
    }
}

// ---------------------------------------------------------------------------
// fused output GEMM, all 3 r per block, double-buffered LDS, K=896:
//   logits[b,n,m,r] = sum_h FG[b*Nn+n, r*HA+h] * Faug[b*Nn+m, h]
// grid (Nn/64, Nn/64, Bb) = 256 blocks; 4 waves (2x2 over n,m), wave = 32x32.
// ---------------------------------------------------------------------------
__global__ __launch_bounds__(256) void gemm_out_fused(
    const bf16_t* __restrict__ FG,    // [Mm, JA]
    const bf16_t* __restrict__ FA,    // [Mm, HA]
    float* __restrict__ OUT)
{
    __shared__ bf16_t S[2][4][64 * 32];  // tiles 0..2 = FG r, 3 = Faug

    const int b = blockIdx.z;
    const int n0 = blockIdx.y * 64;
    const int m0 = blockIdx.x * 64;

    const int tid = threadIdx.x;
    const int w = tid >> 6;
    const int l = tid & 63;

    const int srow = (w << 4) + (l >> 2);
    const int scol = (l & 3) << 3;

    const bf16_t* gh[Rr];
    #pragma unroll
    for (int r = 0; r < Rr; ++r)
        gh[r] = FG + (size_t)(b * Nn + n0 + srow) * JA + r * HA + scol;
    const bf16_t* gt = FA + (size_t)(b * Nn + m0 + srow) * HA + scol;

    const int wn_ = (w >> 1) << 5;  // wave n-offset
    const int wm_ = (w & 1) << 5;   // wave m-offset
    const int fr = l & 15;
    const int fq = (l >> 4) << 3;

    floatx4 acc[Rr][2][2] = {};

    {
        char* base = (char*)&S[0][0][0] + (w << 10);
        #pragma unroll
        for (int r = 0; r < Rr; ++r) { gld_lds16(gh[r], base + r * 4096); gh[r] += 32; }
        gld_lds16(gt, base + 3 * 4096); gt += 32;
    }

    constexpr int STEPS = HA / 32; // 28
    for (int k = 0; k < STEPS; ++k) {
        __syncthreads();
        const int cur = k & 1;
        if (k + 1 < STEPS) {
            char* base = (char*)&S[cur ^ 1][0][0] + (w << 10);
            #pragma unroll
            for (int r = 0; r < Rr; ++r) { gld_lds16(gh[r], base + r * 4096); gh[r] += 32; }
            gld_lds16(gt, base + 3 * 4096); gt += 32;
        }

        bf16x8 t[2];
        #pragma unroll
        for (int j = 0; j < 2; ++j)
            t[j] = *(const bf16x8*)&S[cur][3][(wm_ + j * 16 + fr) * 32 + fq];
        #pragma unroll
        for (int r = 0; r < Rr; ++r) {
            bf16x8 a[2];
            #pragma unroll
            for (int i = 0; i < 2; ++i)
                a[i] = *(const bf16x8*)&S[cur][r][(wn_ + i * 16 + fr) * 32 + fq];
            #pragma unroll
            for (int i = 0; i < 2; ++i)
                #pragma unroll
                for (int j = 0; j < 2; ++j)
                    acc[r][i][j] = __builtin_amdgcn_mfma_f32_16x16x32_bf16(a[i], t[j], acc[r][i][j], 0, 0, 0);
        }
    }

    const int en_ = n0 + wn_ + ((l >> 4) << 2);
    const int em_ = m0 + wm_ + (l & 15);
    #pragma unroll
    for (int i = 0; i < 2; ++i)
        #pragma unroll
        for (int rg = 0; rg < 4; ++rg) {
            const int n = en_ + i * 16 + rg;
            #pragma unroll
            for (int j = 0; j < 2; ++j) {
                const int m = em_ + j * 16;
                float* o = OUT + (((size_t)b * Nn + n) * Nn + m) * Rr;
                #pragma unroll
                for (int r = 0; r < Rr; ++r)
                    o[r] = acc[r][i][j][rg];
            }
        }
}

extern "C" void kernel_launch(void* const* d_in, const int* in_sizes, int n_in,
                              void* d_out, int out_size, void* d_ws, size_t ws_size,
                              hipStream_t stream) {
    const float* features = (const float*)d_in[0]; // [16,256,768]
    const float* head_W   = (const float*)d_in[1]; // [2048,768]
    const float* head_b   = (const float*)d_in[2]; // [2048]
    const float* tail_W   = (const float*)d_in[3]; // [2048,768]
    const float* tail_b   = (const float*)d_in[4]; // [2048]
    const float* bil_W    = (const float*)d_in[5]; // [3,2048,2048]
    const float* bil_b    = (const float*)d_in[6]; // [3]
    float* out = (float*)d_out;                    // [16,256,256,3]

    // workspace layout (bf16), total ~52 MB
    char* ws = (char*)d_ws;
    bf16_t* Faug   = (bf16_t*)ws;  ws += (size_t)Mm * HA * 2;       // 7.3 MB
    bf16_t* tWaug  = (bf16_t*)ws;  ws += (size_t)HA * Pp * 2;       // 3.7 MB
    bf16_t* hWaug  = (bf16_t*)ws;  ws += (size_t)HA * KA * 2;       // 3.7 MB
    bf16_t* T1taug = (bf16_t*)ws;  ws += (size_t)Rr * HA * KA * 2;  // 11.2 MB
    bf16_t* Bop    = (bf16_t*)ws;  ws += (size_t)Rr * HA * HA * 2;  // 4.8 MB
    bf16_t* FG     = (bf16_t*)ws;  ws += (size_t)Mm * JA * 2;       // 22.0 MB

    // 1) build augmented operands (tiny/streaming; bil_W is consumed fp32-direct)
    build_Faug<<<Mm * (HA / 4) / 256, 256, 0, stream>>>(features, Faug);
    build_tWaug<<<dim3(Pp / 32, HA / 32), dim3(32, 8), 0, stream>>>(tail_W, tail_b, tWaug);
    build_hWaug<<<dim3(KA / 32, HA / 32), dim3(32, 8), 0, stream>>>(head_W, head_b, hWaug);

    // 2) T1taug[r] [896, 2048(+32)] = tWaug [896,2048] @ bil_W[r]^T (B fp32 direct)
    gemm_nt_64_bf32<<<dim3(Pp / 64, HA / 64, Rr), 256, 0, stream>>>(
        tWaug, Pp,
        bil_W, Pp, (size_t)Pp * Pp,
        T1taug, KA, (size_t)HA * KA, Pp);
    fill_T1cols<<<(Rr * HA + 255) / 256, 256, 0, stream>>>(bil_b, T1taug);

    // 3) Bop[r] [896, 896] = T1taug[r] [896,2080] @ hWaug^T [896,2080]
    gemm_nt_64<<<dim3(HA / 64, HA / 64, Rr), 256, 0, stream>>>(
        T1taug, KA, (size_t)HA * KA,
        hWaug, KA, 0,
        Bop, HA, (size_t)HA * HA, KA);

    // 4) FG [4096, 2688] = Faug [4096,896] @ Bop^T [2688,896]
    gemm_nt_128<<<dim3(JA / 128, Mm / 128), 256, 0, stream>>>(
        Faug, HA,
        Bop, HA,
        FG, JA, HA);

    // 5) fused output GEMM over all r (K=896, biases already folded in)
    gemm_out_fused<<<dim3(Nn / 64, Nn / 64, Bb), 256, 0, stream>>>(FG, Faug, out);
}

// Round 7
// 261.434 us; speedup vs baseline: 1.0354x; 1.0354x over previous
//
#include <hip/hip_runtime.h>

// Problem constants
constexpr int Bb = 16;      // batch
constexpr int Nn = 256;     // regions
constexpr int Hh = 768;     // hidden
constexpr int Pp = 2048;    // proj dim
constexpr int Rr = 3;       // relation types
constexpr int Mm = Bb * Nn; // 4096 flattened rows
constexpr int HA = 896;     // augmented hidden (768 + 1 bias row + pad)
constexpr int KA = 2080;    // augmented K for Bop GEMM (2048 + 32)
constexpr int JA = Rr * HA; // 2688

typedef __bf16 bf16_t;
typedef __bf16 bf16x8 __attribute__((ext_vector_type(8)));
typedef __bf16 bf16x4 __attribute__((ext_vector_type(4)));
typedef float  floatx4 __attribute__((ext_vector_type(4)));

// async global->LDS, 16B per lane; LDS dest = wave-uniform base + lane*16
__device__ __forceinline__ void gld_lds16(const void* g, void* l) {
    __builtin_amdgcn_global_load_lds(
        (__attribute__((address_space(1))) void*)g,
        (__attribute__((address_space(3))) void*)l,
        16, 0, 0);
}

// ---------------------------------------------------------------------------
// F_aug [4096, 896] bf16: cols 0..767 = F, col 768 = 1, cols 769..895 = 0
// ---------------------------------------------------------------------------
__global__ __launch_bounds__(256) void build_Faug(
    const float* __restrict__ F, bf16_t* __restrict__ out)
{
    const int idx = blockIdx.x * 256 + threadIdx.x;   // over 4096 * (896/4)
    const int n = idx / (HA / 4), c4 = idx % (HA / 4);
    const int h = c4 * 4;
    bf16x4 o;
    if (h < Hh) {
        float4 v = *(const float4*)(F + (size_t)n * Hh + h);
        o = { (bf16_t)v.x, (bf16_t)v.y, (bf16_t)v.z, (bf16_t)v.w };
    } else {
        #pragma unroll
        for (int e = 0; e < 4; ++e) o[e] = (bf16_t)((h + e == Hh) ? 1.0f : 0.0f);
    }
    *(bf16x4*)(out + (size_t)n * HA + h) = o;
}

// ---------------------------------------------------------------------------
// tWaug [896, 2048]: rows j<768 = tW^T (tW[q,j]), row 768 = bt[q], rows>768 = 0
// ---------------------------------------------------------------------------
__global__ __launch_bounds__(256) void build_tWaug(
    const float* __restrict__ tW, const float* __restrict__ bt,
    bf16_t* __restrict__ out)
{
    __shared__ float t[32][33];
    const int j0 = blockIdx.y * 32, q0 = blockIdx.x * 32;
    const int tx = threadIdx.x, ty = threadIdx.y;
    #pragma unroll
    for (int s = 0; s < 4; ++s) {
        const int q = q0 + ty + s * 8, j = j0 + tx;
        t[ty + s * 8][tx] = (j < Hh) ? tW[(size_t)q * Hh + j] : 0.0f;
    }
    __syncthreads();
    #pragma unroll
    for (int s = 0; s < 4; ++s) {
        const int j = j0 + ty + s * 8, q = q0 + tx;
        float v = t[tx][ty + s * 8];
        if (j == Hh) v = bt[q];
        else if (j > Hh) v = 0.0f;
        out[(size_t)j * Pp + q] = (bf16_t)v;
    }
}

// ---------------------------------------------------------------------------
// hWaug [896, 2080]: rows h<768 = hW^T, row 768 = [bh | 1 @ p=2048], rows>768=0
// ---------------------------------------------------------------------------
__global__ __launch_bounds__(256) void build_hWaug(
    const float* __restrict__ hW, const float* __restrict__ bh,
    bf16_t* __restrict__ out)
{
    __shared__ float t[32][33];
    const int h0 = blockIdx.y * 32, p0 = blockIdx.x * 32;
    const int tx = threadIdx.x, ty = threadIdx.y;
    #pragma unroll
    for (int s = 0; s < 4; ++s) {
        const int p = p0 + ty + s * 8, h = h0 + tx;
        t[ty + s * 8][tx] = (p < Pp && h < Hh) ? hW[(size_t)p * Hh + h] : 0.0f;
    }
    __syncthreads();
    #pragma unroll
    for (int s = 0; s < 4; ++s) {
        const int h = h0 + ty + s * 8, p = p0 + tx;
        float v = t[tx][ty + s * 8];
        if (h == Hh) v = (p < Pp) ? bh[p] : (p == Pp ? 1.0f : 0.0f);
        else if (h > Hh) v = 0.0f;
        out[(size_t)h * KA + p] = (bf16_t)v;
    }
}

// ---------------------------------------------------------------------------
// fill T1taug col stripe [j][2048..2079]: col 2048 = (j==768 ? bil_b[r] : 0)
// ---------------------------------------------------------------------------
__global__ __launch_bounds__(256) void fill_T1cols(
    const float* __restrict__ bil_b, bf16_t* __restrict__ T1)
{
    const int idx = blockIdx.x * 256 + threadIdx.x;
    if (idx >= Rr * HA) return;
    const int r = idx / HA, j = idx % HA;
    bf16_t* p = T1 + (size_t)r * HA * KA + (size_t)j * KA + Pp;
    p[0] = (bf16_t)(j == Hh ? bil_b[r] : 0.0f);
    #pragma unroll
    for (int e = 1; e < 32; ++e) p[e] = (bf16_t)0.0f;
}

// ---------------------------------------------------------------------------
// 128(M)x64(N)-tile NT GEMM, A bf16 / B fp32 (in-kernel cvt), dbuf LDS,
// XOR-swizzled fp32 B staging. 4 waves (2x2), wave = 64x32 -> 8 MFMA/step
// per 2 cvt'd B fragments (2x the MFMA density of the 64x64 version).
//   C[m,n] = sum_k A[m,k] * B[n,k];  T1 = tWaug @ bil_W[r]^T
// grid (N/64, M/128, R)
// ---------------------------------------------------------------------------
__global__ __launch_bounds__(256) void gemm_nt_128x64_bf32(
    const bf16_t* __restrict__ A, int lda,
    const float*  __restrict__ B, int ldb, size_t sB,
    bf16_t* __restrict__ C, int ldc, size_t sC, int K)
{
    B += (size_t)blockIdx.z * sB;
    C += (size_t)blockIdx.z * sC;

    __shared__ bf16_t As[2][128 * 32];   // 8 KB per buf
    __shared__ float  Bs[2][64 * 32];    // 8 KB per buf

    const int tid = threadIdx.x;
    const int w = tid >> 6;
    const int l = tid & 63;
    const int m0 = blockIdx.y * 128;
    const int n0 = blockIdx.x * 64;

    // A staging (bf16, 128x32 = 8KB, 2 issues): row = i*64 + w*16 + l/4
    const bf16_t* ga0 = A + (size_t)(m0 + (w << 4) + (l >> 2)) * lda + ((l & 3) << 3);
    const bf16_t* ga1 = ga0 + (size_t)64 * lda;
    // B staging (fp32, 64x32 = 8KB, 2 issues), swizzled: physical col-group
    // (l&7) holds global col-group (l&7)^(row&7); row = i*32 + w*8 + l/8,
    // so row&7 = l>>3 for both issues.
    const int brow = (w << 3) + (l >> 3);
    const int bgrp = (l & 7) ^ (l >> 3);
    const float* gb0 = B + (size_t)(n0 + brow) * ldb + (bgrp << 2);
    const float* gb1 = gb0 + (size_t)32 * ldb;

    const int wm = (w >> 1) << 6;    // wave M-offset: 0/64
    const int wn = (w & 1) << 5;     // wave N-offset: 0/32
    const int fr = l & 15;
    const int fq = (l >> 4) << 3;

    // swizzled fragment-read col offsets (floats); row&7 == fr&7
    const int swz = fr & 7;
    const int cg0 = (l >> 4) << 1;
    const int off0 = ((cg0 ^ swz) << 2);
    const int off1 = (((cg0 + 1) ^ swz) << 2);

    floatx4 acc[4][2] = {};

    {
        gld_lds16(ga0, (char*)As[0] + (w << 10));
        gld_lds16(ga1, (char*)As[0] + 4096 + (w << 10));
        gld_lds16(gb0, (char*)Bs[0] + (w << 10));
        gld_lds16(gb1, (char*)Bs[0] + 4096 + (w << 10));
        ga0 += 32; ga1 += 32; gb0 += 32; gb1 += 32;
    }

    const int steps = K >> 5;
    for (int k = 0; k < steps; ++k) {
        __syncthreads();
        const int cur = k & 1;
        if (k + 1 < steps) {
            gld_lds16(ga0, (char*)As[cur ^ 1] + (w << 10));
            gld_lds16(ga1, (char*)As[cur ^ 1] + 4096 + (w << 10));
            gld_lds16(gb0, (char*)Bs[cur ^ 1] + (w << 10));
            gld_lds16(gb1, (char*)Bs[cur ^ 1] + 4096 + (w << 10));
            ga0 += 32; ga1 += 32; gb0 += 32; gb1 += 32;
        }

        bf16x8 a[4], b[2];
        #pragma unroll
        for (int i = 0; i < 4; ++i)
            a[i] = *(const bf16x8*)&As[cur][(wm + i * 16 + fr) * 32 + fq];
        #pragma unroll
        for (int j = 0; j < 2; ++j) {
            const float* bp = &Bs[cur][(wn + j * 16 + fr) * 32];
            floatx4 x0 = *(const floatx4*)(bp + off0);
            floatx4 x1 = *(const floatx4*)(bp + off1);
            #pragma unroll
            for (int e = 0; e < 4; ++e) { b[j][e] = (bf16_t)x0[e]; b[j][e + 4] = (bf16_t)x1[e]; }
        }
        #pragma unroll
        for (int i = 0; i < 4; ++i)
            #pragma unroll
            for (int j = 0; j < 2; ++j)
                acc[i][j] = __builtin_amdgcn_mfma_f32_16x16x32_bf16(a[i], b[j], acc[i][j], 0, 0, 0);
    }

    const int em = m0 + wm + ((l >> 4) << 2);
    const int en = n0 + wn + (l & 15);
    #pragma unroll
    for (int i = 0; i < 4; ++i)
        #pragma unroll
        for (int j = 0; j < 2; ++j)
            #pragma unroll
            for (int rg = 0; rg < 4; ++rg)
                C[(size_t)(em + i * 16 + rg) * ldc + en + j * 16] = (bf16_t)acc[i][j][rg];
}

// ---------------------------------------------------------------------------
// 64x64-tile bf16 NT GEMM, double-buffered LDS (for Bop)
// ---------------------------------------------------------------------------
__global__ __launch_bounds__(256) void gemm_nt_64(
    const bf16_t* __restrict__ A, int lda, size_t sA,
    const bf16_t* __restrict__ B, int ldb, size_t sB,
    bf16_t* __restrict__ C, int ldc, size_t sC, int K)
{
    A += (size_t)blockIdx.z * sA;
    B += (size_t)blockIdx.z * sB;
    C += (size_t)blockIdx.z * sC;

    __shared__ bf16_t As[2][64 * 32];
    __shared__ bf16_t Bs[2][64 * 32];

    const int tid = threadIdx.x;
    const int w = tid >> 6;
    const int l = tid & 63;
    const int m0 = blockIdx.y * 64;
    const int n0 = blockIdx.x * 64;

    const bf16_t* ga = A + (size_t)(m0 + (tid >> 2)) * lda + ((tid & 3) << 3);
    const bf16_t* gb = B + (size_t)(n0 + (tid >> 2)) * ldb + ((tid & 3) << 3);

    const int wm = (w >> 1) << 5;
    const int wn = (w & 1) << 5;
    const int fr = l & 15;
    const int fq = (l >> 4) << 3;

    floatx4 acc[2][2] = {};

    {
        gld_lds16(ga, (char*)As[0] + (w << 10));
        gld_lds16(gb, (char*)Bs[0] + (w << 10));
        ga += 32; gb += 32;
    }

    const int steps = K >> 5;
    for (int k = 0; k < steps; ++k) {
        __syncthreads();
        const int cur = k & 1;
        if (k + 1 < steps) {
            gld_lds16(ga, (char*)As[cur ^ 1] + (w << 10));
            gld_lds16(gb, (char*)Bs[cur ^ 1] + (w << 10));
            ga += 32; gb += 32;
        }

        bf16x8 a[2], b[2];
        #pragma unroll
        for (int i = 0; i < 2; ++i) {
            a[i] = *(const bf16x8*)&As[cur][(wm + i * 16 + fr) * 32 + fq];
            b[i] = *(const bf16x8*)&Bs[cur][(wn + i * 16 + fr) * 32 + fq];
        }
        #pragma unroll
        for (int i = 0; i < 2; ++i)
            #pragma unroll
            for (int j = 0; j < 2; ++j)
                acc[i][j] = __builtin_amdgcn_mfma_f32_16x16x32_bf16(a[i], b[j], acc[i][j], 0, 0, 0);
    }

    const int em = m0 + wm + ((l >> 4) << 2);
    const int en = n0 + wn + (l & 15);
    #pragma unroll
    for (int i = 0; i < 2; ++i)
        #pragma unroll
        for (int j = 0; j < 2; ++j)
            #pragma unroll
            for (int rg = 0; rg < 4; ++rg)
                C[(size_t)(em + i * 16 + rg) * ldc + en + j * 16] = (bf16_t)acc[i][j][rg];
}

// ---------------------------------------------------------------------------
// 128x128-tile bf16 NT GEMM, double-buffered LDS (for FG)
// ---------------------------------------------------------------------------
__global__ __launch_bounds__(256) void gemm_nt_128(
    const bf16_t* __restrict__ A, int lda,
    const bf16_t* __restrict__ B, int ldb,
    bf16_t* __restrict__ C, int ldc, int K)
{
    __shared__ bf16_t As[2][128 * 32];
    __shared__ bf16_t Bs[2][128 * 32];

    const int tid = threadIdx.x;
    const int w = tid >> 6;
    const int l = tid & 63;
    const int m0 = blockIdx.y * 128;
    const int n0 = blockIdx.x * 128;

    const int srow = (w << 4) + (l >> 2);
    const int scol = (l & 3) << 3;
    const bf16_t* ga0 = A + (size_t)(m0 + srow) * lda + scol;
    const bf16_t* ga1 = ga0 + (size_t)64 * lda;
    const bf16_t* gb0 = B + (size_t)(n0 + srow) * ldb + scol;
    const bf16_t* gb1 = gb0 + (size_t)64 * ldb;

    const int wm = (w >> 1) << 6;
    const int wn = (w & 1) << 6;
    const int fr = l & 15;
    const int fq = (l >> 4) << 3;

    floatx4 acc[4][4] = {};

    {
        char* a = (char*)As[0] + (w << 10);
        char* b = (char*)Bs[0] + (w << 10);
        gld_lds16(ga0, a); gld_lds16(ga1, a + 4096);
        gld_lds16(gb0, b); gld_lds16(gb1, b + 4096);
        ga0 += 32; ga1 += 32; gb0 += 32; gb1 += 32;
    }

    const int steps = K >> 5;
    for (int k = 0; k < steps; ++k) {
        __syncthreads();
        const int cur = k & 1;
        if (k + 1 < steps) {
            char* a = (char*)As[cur ^ 1] + (w << 10);
            char* b = (char*)Bs[cur ^ 1] + (w << 10);
            gld_lds16(ga0, a); gld_lds16(ga1, a + 4096);
            gld_lds16(gb0, b); gld_lds16(gb1, b + 4096);
            ga0 += 32; ga1 += 32; gb0 += 32; gb1 += 32;
        }

        bf16x8 a[4], b[4];
        #pragma unroll
        for (int i = 0; i < 4; ++i) {
            a[i] = *(const bf16x8*)&As[cur][(wm + i * 16 + fr) * 32 + fq];
            b[i] = *(const bf16x8*)&Bs[cur][(wn + i * 16 + fr) * 32 + fq];
        }
        #pragma unroll
        for (int i = 0; i < 4; ++i)
            #pragma unroll
            for (int j = 0; j < 4; ++j)
                acc[i][j] = __builtin_amdgcn_mfma_f32_16x16x32_bf16(a[i], b[j], acc[i][j], 0, 0, 0);
    }

    const int em = m0 + wm + ((l >> 4) << 2);
    const int en = n0 + wn + (l & 15);
    #pragma unroll
    for (int j = 0; j < 4; ++j) {
        const int n = en + j * 16;
        #pragma unroll
        for (int i = 0; i < 4; ++i) {
            #pragma unroll
            for (int rg = 0; rg < 4; ++rg)
                C[(size_t)(em + i * 16 + rg) * ldc + n] = (bf16_t)(acc[i][j][rg]);
        }
    }
}

// ---------------------------------------------------------------------------
// fused output GEMM, all 3 r per block, dbuf LDS, K=896, 512 threads (8 waves
// -> 2 waves/SIMD at 1 block/CU; wave = 32n x 16m, 6 MFMA/step):
//   logits[b,n,m,r] = sum_h FG[b*Nn+n, r*HA+h] * Faug[b*Nn+m, h]
// grid (Nn/64, Nn/64, Bb) = 256 blocks.
// ---------------------------------------------------------------------------
__global__ __launch_bounds__(512) void gemm_out_fused(
    const bf16_t* __restrict__ FG,    // [Mm, JA]
    const bf16_t* __restrict__ FA,    // [Mm, HA]
    float* __restrict__ OUT)
{
    __shared__ bf16_t S[2][4][64 * 32];  // tiles 0..2 = FG r, 3 = Faug (32KB)

    const int b = blockIdx.z;
    const int n0 = blockIdx.y * 64;
    const int m0 = blockIdx.x * 64;

    const int tid = threadIdx.x;
    const int w = tid >> 6;      // 0..7
    const int l = tid & 63;

    // staging: 16KB/step over 512 lanes = 2 issues of 16B.
    // issue i, wave w covers LDS bytes i*8192 + w*1024 + l*16
    //   -> tile = 2i + (w>>2), row = (w&3)*16 + l/4, col8 = (l&3)*8
    const int srow = ((w & 3) << 4) + (l >> 2);
    const int scol = (l & 3) << 3;
    const int t0 = w >> 2;               // issue0 tile: FG r = 0/1
    const bf16_t* g0 = FG + (size_t)(b * Nn + n0 + srow) * JA + t0 * HA + scol;
    const bf16_t* g1 = (t0 == 0)
        ? FG + (size_t)(b * Nn + n0 + srow) * JA + 2 * HA + scol   // tile2: FG r=2
        : FA + (size_t)(b * Nn + m0 + srow) * HA + scol;           // tile3: Faug

    const int n_off = (w >> 2) << 5;     // 0/32
    const int m_off = (w & 3) << 4;      // 0/16/32/48
    const int fr = l & 15;
    const int fq = (l >> 4) << 3;

    floatx4 acc[Rr][2] = {};

    {
        char* base = (char*)&S[0][0][0];
        gld_lds16(g0, base + (w << 10));        g0 += 32;
        gld_lds16(g1, base + 8192 + (w << 10)); g1 += 32;
    }

    constexpr int STEPS = HA / 32; // 28
    for (int k = 0; k < STEPS; ++k) {
        __syncthreads();
        const int cur = k & 1;
        if (k + 1 < STEPS) {
            char* base = (char*)&S[cur ^ 1][0][0];
            gld_lds16(g0, base + (w << 10));        g0 += 32;
            gld_lds16(g1, base + 8192 + (w << 10)); g1 += 32;
        }

        bf16x8 t = *(const bf16x8*)&S[cur][3][(m_off + fr) * 32 + fq];
        #pragma unroll
        for (int r = 0; r < Rr; ++r) {
            #pragma unroll
            for (int i = 0; i < 2; ++i) {
                bf16x8 a = *(const bf16x8*)&S[cur][r][(n_off + i * 16 + fr) * 32 + fq];
                acc[r][i] = __builtin_amdgcn_mfma_f32_16x16x32_bf16(a, t, acc[r][i], 0, 0, 0);
            }
        }
    }

    const int en_ = n0 + n_off + ((l >> 4) << 2);
    const int em_ = m0 + m_off + (l & 15);
    #pragma unroll
    for (int i = 0; i < 2; ++i)
        #pragma unroll
        for (int rg = 0; rg < 4; ++rg) {
            const int n = en_ + i * 16 + rg;
            float* o = OUT + (((size_t)b * Nn + n) * Nn + em_) * Rr;
            #pragma unroll
            for (int r = 0; r < Rr; ++r)
                o[r] = acc[r][i][rg];
        }
}

extern "C" void kernel_launch(void* const* d_in, const int* in_sizes, int n_in,
                              void* d_out, int out_size, void* d_ws, size_t ws_size,
                              hipStream_t stream) {
    const float* features = (const float*)d_in[0]; // [16,256,768]
    const float* head_W   = (const float*)d_in[1]; // [2048,768]
    const float* head_b   = (const float*)d_in[2]; // [2048]
    const float* tail_W   = (const float*)d_in[3]; // [2048,768]
    const float* tail_b   = (const float*)d_in[4]; // [2048]
    const float* bil_W    = (const float*)d_in[5]; // [3,2048,2048]
    const float* bil_b    = (const float*)d_in[6]; // [3]
    float* out = (float*)d_out;                    // [16,256,256,3]

    // workspace layout (bf16), total ~52 MB
    char* ws = (char*)d_ws;
    bf16_t* Faug   = (bf16_t*)ws;  ws += (size_t)Mm * HA * 2;       // 7.3 MB
    bf16_t* tWaug  = (bf16_t*)ws;  ws += (size_t)HA * Pp * 2;       // 3.7 MB
    bf16_t* hWaug  = (bf16_t*)ws;  ws += (size_t)HA * KA * 2;       // 3.7 MB
    bf16_t* T1taug = (bf16_t*)ws;  ws += (size_t)Rr * HA * KA * 2;  // 11.2 MB
    bf16_t* Bop    = (bf16_t*)ws;  ws += (size_t)Rr * HA * HA * 2;  // 4.8 MB
    bf16_t* FG     = (bf16_t*)ws;  ws += (size_t)Mm * JA * 2;       // 22.0 MB

    // 1) build augmented operands (tiny/streaming; bil_W is consumed fp32-direct)
    build_Faug<<<Mm * (HA / 4) / 256, 256, 0, stream>>>(features, Faug);
    build_tWaug<<<dim3(Pp / 32, HA / 32), dim3(32, 8), 0, stream>>>(tail_W, tail_b, tWaug);
    build_hWaug<<<dim3(KA / 32, HA / 32), dim3(32, 8), 0, stream>>>(head_W, head_b, hWaug);

    // 2) T1taug[r] [896, 2048(+32)] = tWaug [896,2048] @ bil_W[r]^T (B fp32 direct)
    gemm_nt_128x64_bf32<<<dim3(Pp / 64, HA / 128, Rr), 256, 0, stream>>>(
        tWaug, Pp,
        bil_W, Pp, (size_t)Pp * Pp,
        T1taug, KA, (size_t)HA * KA, Pp);
    fill_T1cols<<<(Rr * HA + 255) / 256, 256, 0, stream>>>(bil_b, T1taug);

    // 3) Bop[r] [896, 896] = T1taug[r] [896,2080] @ hWaug^T [896,2080]
    gemm_nt_64<<<dim3(HA / 64, HA / 64, Rr), 256, 0, stream>>>(
        T1taug, KA, (size_t)HA * KA,
        hWaug, KA, 0,
        Bop, HA, (size_t)HA * HA, KA);

    // 4) FG [4096, 2688] = Faug [4096,896] @ Bop^T [2688,896]
    gemm_nt_128<<<dim3(JA / 128, Mm / 128), 256, 0, stream>>>(
        Faug, HA,
        Bop, HA,
        FG, JA, HA);

    // 5) fused output GEMM over all r (K=896, biases already folded in)
    gemm_out_fused<<<dim3(Nn / 64, Nn / 64, Bb), 512, 0, stream>>>(FG, Faug, out);
}